// Round 3
// baseline (225.362 us; speedup 1.0000x reference)
//
#include <hip/hip_runtime.h>
#include <stdint.h>

// ---- types ----
typedef __attribute__((ext_vector_type(8))) short short8;   // 8 bf16 (4 VGPRs)
typedef __attribute__((ext_vector_type(4))) float f32x4;    // MFMA acc
typedef unsigned short u16;

// B=2, S=2048, E=1024, H=16, DK=64
#define SEQ 2048
#define EMB 1024
#define NH 16
#define DK 64
#define MTOT 4096   // B*S
#define CEXP 0.18033688011112042f   // 0.125 * log2(e): fold qk-scale into exp2

__device__ __forceinline__ u16 f2bf(float f) {
  union { float f; unsigned int u; } x; x.f = f;
  unsigned int r = x.u + 0x7fffu + ((x.u >> 16) & 1u);  // RNE
  return (u16)(r >> 16);
}

// async global->LDS, 16B per lane. LDS dest = wave-uniform base + lane*16.
__device__ __forceinline__ void gload_lds16(const void* g, void* l) {
  __builtin_amdgcn_global_load_lds(
      (const __attribute__((address_space(1))) unsigned int*)g,
      (__attribute__((address_space(3))) unsigned int*)l,
      16, 0, 0);
}

// ---------------- fp32 -> bf16 converts (fused launches) ----------------
__global__ __launch_bounds__(256) void cvt3(const float* __restrict__ a,
                                            const float* __restrict__ b,
                                            const float* __restrict__ c,
                                            u16* __restrict__ d) {
  const float* s = (blockIdx.y == 0) ? a : ((blockIdx.y == 1) ? b : c);
  size_t base = (size_t)blockIdx.y * (MTOT * (size_t)EMB / 4);
  int i = blockIdx.x * 256 + threadIdx.x;
  float4 v = ((const float4*)s)[i];
  ushort4 o;
  o.x = f2bf(v.x); o.y = f2bf(v.y); o.z = f2bf(v.z); o.w = f2bf(v.w);
  ((ushort4*)d)[base + i] = o;
}

__global__ __launch_bounds__(256) void cvt4(const float* __restrict__ a,
                                            const float* __restrict__ b,
                                            const float* __restrict__ c,
                                            const float* __restrict__ e,
                                            u16* __restrict__ d) {
  const float* s = (blockIdx.y == 0) ? a
                 : ((blockIdx.y == 1) ? b : ((blockIdx.y == 2) ? c : e));
  size_t base = (size_t)blockIdx.y * ((size_t)EMB * EMB / 4);
  int i = blockIdx.x * 256 + threadIdx.x;
  float4 v = ((const float4*)s)[i];
  ushort4 o;
  o.x = f2bf(v.x); o.y = f2bf(v.y); o.z = f2bf(v.z); o.w = f2bf(v.w);
  ((ushort4*)d)[base + i] = o;
}

// ---------------- GEMM core: C[M,N] = A[M,K] @ W[N,K]^T + bias ----------------
// BM=BN=128, BK=64, 256 threads = 4 waves (2x2), each wave 64x64 (4x4 frags).
// MODE 0: store bf16 into [B,H,S,DK] head layout. MODE 1: store fp32 flat [M,N].
template <int MODE>
__device__ __forceinline__ void gemm_core(const u16* __restrict__ A,
                                          const u16* __restrict__ W,
                                          const float* __restrict__ bias,
                                          void* __restrict__ dst,
                                          int m0, int n0,
                                          u16* As, u16* Bs) {
  const int K = EMB;
  int tid = threadIdx.x, lane = tid & 63, wid = tid >> 6;
  int g = lane >> 4, l15 = lane & 15;
  int wr = wid >> 1, wc = wid & 1;

  f32x4 acc[4][4];
#pragma unroll
  for (int mi = 0; mi < 4; ++mi)
#pragma unroll
    for (int ni = 0; ni < 4; ++ni) acc[mi][ni] = (f32x4)(0.0f);

  for (int kt = 0; kt < K / 64; ++kt) {
    int k0 = kt * 64;
#pragma unroll
    for (int i = 0; i < 4; ++i) {
      int off = (wid * 4 + i) * 1024;          // byte offset into tile
      int elem = (off >> 1) + lane * 8;        // bf16 element index
      int row = elem >> 6, col = elem & 63;
      gload_lds16(A + (size_t)(m0 + row) * K + k0 + col, (char*)As + off);
      gload_lds16(W + (size_t)(n0 + row) * K + k0 + col, (char*)Bs + off);
    }
    __syncthreads();  // drains vmcnt
#pragma unroll
    for (int kk = 0; kk < 2; ++kk) {
      short8 af[4], bf[4];
#pragma unroll
      for (int mi = 0; mi < 4; ++mi)
        af[mi] = *(const short8*)&As[(wr * 64 + mi * 16 + l15) * 64 + kk * 32 + 8 * g];
#pragma unroll
      for (int ni = 0; ni < 4; ++ni)
        bf[ni] = *(const short8*)&Bs[(wc * 64 + ni * 16 + l15) * 64 + kk * 32 + 8 * g];
#pragma unroll
      for (int mi = 0; mi < 4; ++mi)
#pragma unroll
        for (int ni = 0; ni < 4; ++ni)
          acc[mi][ni] = __builtin_amdgcn_mfma_f32_16x16x32_bf16(af[mi], bf[ni],
                                                                acc[mi][ni], 0, 0, 0);
    }
    __syncthreads();
  }

  // epilogue: D layout col=lane&15, row=(lane>>4)*4+j  [m89-verified]
#pragma unroll
  for (int ni = 0; ni < 4; ++ni) {
    int n_g = n0 + wc * 64 + ni * 16 + l15;
    float bv = bias[n_g];
#pragma unroll
    for (int mi = 0; mi < 4; ++mi) {
#pragma unroll
      for (int j = 0; j < 4; ++j) {
        int m_g = m0 + wr * 64 + mi * 16 + 4 * g + j;
        float v = acc[mi][ni][j] + bv;
        if (MODE == 0) {
          int b = m_g >> 11, s = m_g & (SEQ - 1);
          int h = n_g >> 6, d = n_g & 63;
          ((u16*)dst)[((((size_t)b * NH + h) * SEQ + s) << 6) + d] = f2bf(v);
        } else {
          ((float*)dst)[(size_t)m_g * EMB + n_g] = v;
        }
      }
    }
  }
}

__global__ __launch_bounds__(256, 2) void gemm_qkv(const u16* __restrict__ Aall,
                                                   const u16* __restrict__ Wall,
                                                   const float* __restrict__ bq,
                                                   const float* __restrict__ bk,
                                                   const float* __restrict__ bv,
                                                   u16* __restrict__ QKVh) {
  __shared__ __align__(16) u16 As[128 * 64];
  __shared__ __align__(16) u16 Bs[128 * 64];
  int z = blockIdx.z;
  const u16* A = Aall + (size_t)z * MTOT * EMB;
  const u16* W = Wall + (size_t)z * EMB * EMB;
  const float* bias = (z == 0) ? bq : ((z == 1) ? bk : bv);
  u16* dst = QKVh + (size_t)z * MTOT * EMB;
  gemm_core<0>(A, W, bias, dst, blockIdx.y * 128, blockIdx.x * 128, As, Bs);
}

__global__ __launch_bounds__(256, 2) void gemm_out(const u16* __restrict__ X,
                                                   const u16* __restrict__ Wo,
                                                   const float* __restrict__ bo,
                                                   float* __restrict__ out) {
  __shared__ __align__(16) u16 As[128 * 64];
  __shared__ __align__(16) u16 Bs[128 * 64];
  gemm_core<1>(X, Wo, bo, out, blockIdx.y * 128, blockIdx.x * 128, As, Bs);
}

// ---------------- flash attention (causal), swapped-QK^T version ----------------
// 1D grid of 1024 blocks; decode: xcd = bl&7 groups 4 bh per XCD (L2 locality),
// qt heavy-first. 256 threads = 4 waves, wave w owns q rows [q0+16w, q0+16w+16).
//
// QK^T computed SWAPPED: sc = mfma(K_frag, Q_frag) -> lane holds q = qw + (lane&15),
// kv in registers. K rows loaded with permutation sigma(c, r) = 8*(r>>2)+(r&3)
// + 4*(c&1) + 32*(c>>1), so lane (l15, g) owns kv offsets {8g..8g+7} u {32+8g..+7}
// == exactly the PV B-fragment layout (k = 8*(lane>>4)+j). Softmax is lane-local:
// 15 in-reg max + 2 shfl_xor; P packs in-register via v_cvt_pk_bf16_f32.
// O accumulates transposed: oacc[c2][j] -> d = 16*c2 + 4*g + j, q = qw + l15;
// rescale is lane-local. Epilogue transposes O through freed Vt LDS.
__global__ __launch_bounds__(256, 4) void flash_attn(const u16* __restrict__ Qh,
                                                     const u16* __restrict__ Kh,
                                                     const u16* __restrict__ Vh,
                                                     u16* __restrict__ X) {
  __shared__ __align__(16) u16 Vt[64][72];      // [d][kv], pad->144B rows

  int tid = threadIdx.x, lane = tid & 63, wid = tid >> 6;
  int g = lane >> 4, l15 = lane & 15;

  int bl = blockIdx.x;
  int xcd = bl & 7, idx = bl >> 3;              // 128 blocks per XCD
  int bh = xcd * 4 + (idx >> 5);                // 4 bh per XCD -> K/V L2-resident
  int qt = 31 - (idx & 31);                     // heavy blocks first

  int q0 = qt * 64, qw = q0 + wid * 16;
  int qrow = qw + l15;                          // this lane's q row

  // Q fragment (B-operand): rows q = qw+l15, k = 8g+j (halves at +0 / +32)
  const short8* qp = (const short8*)(Qh + ((size_t)bh * SEQ + qrow) * DK + 8 * g);
  short8 fq0 = qp[0], fq1 = qp[4];

  int kvbase = 8 * (l15 >> 2) + (l15 & 3);      // sigma row base for this lane
  const u16* Kb = Kh + (size_t)bh * SEQ * DK;
  const u16* Vb = Vh + (size_t)bh * SEQ * DK;

  f32x4 sc[4], oacc[4];
#pragma unroll
  for (int i = 0; i < 4; ++i) oacc[i] = (f32x4)(0.0f);
  float m_run = -1e30f, l_run = 0.0f;

  for (int t = 0; t <= qt; ++t) {
    int kv0 = t * 64;
    __syncthreads();  // prev PV done reading Vt
    // stage V[kv0+0..63][d] -> Vt[d][kv] (transpose; coalesced global reads)
#pragma unroll
    for (int it = 0; it < 2; ++it) {
      int kvb = wid * 8 + it * 32;
      short8 tmp;
#pragma unroll
      for (int i = 0; i < 8; ++i)
        tmp[i] = (short)Vb[(size_t)(kv0 + kvb + i) * DK + lane];
      *(short8*)&Vt[lane][kvb] = tmp;
    }

    // QK^T swapped, K rows permuted by sigma
    const u16* krow = Kb + (size_t)(kv0 + kvbase) * DK + 8 * g;
#pragma unroll
    for (int c = 0; c < 4; ++c) {
      const u16* kc = krow + (size_t)(4 * (c & 1) + 32 * (c >> 1)) * DK;
      short8 k0 = *(const short8*)kc;
      short8 k1 = *(const short8*)(kc + 32);
      f32x4 z = (f32x4)(0.0f);
      z = __builtin_amdgcn_mfma_f32_16x16x32_bf16(k0, fq0, z, 0, 0, 0);
      z = __builtin_amdgcn_mfma_f32_16x16x32_bf16(k1, fq1, z, 0, 0, 0);
      sc[c] = z;
    }
    __syncthreads();  // Vt staged for this tile

    // causal mask (diag tile only); lane's sc[c][j] is kv = kv0+8g+4(c&1)+32(c>>1)+j
    if (t == qt) {
#pragma unroll
      for (int c = 0; c < 4; ++c) {
        int kvc = kv0 + 8 * g + 4 * (c & 1) + 32 * (c >> 1);
#pragma unroll
        for (int j = 0; j < 4; ++j)
          if (kvc + j > qrow) sc[c][j] = -1e30f;
      }
    }

    // row max: 15 in-register + 2 shfl (lanes l15, l15+16, +32, +48 share q)
    float vmax = sc[0][0];
#pragma unroll
    for (int c = 0; c < 4; ++c)
#pragma unroll
      for (int j = 0; j < 4; ++j) vmax = fmaxf(vmax, sc[c][j]);
    vmax = fmaxf(vmax, __shfl_xor(vmax, 16));
    vmax = fmaxf(vmax, __shfl_xor(vmax, 32));

    // defer-max (T13): raw-score threshold 44 -> p bounded by ~2^8
    if (!__all(vmax - m_run <= 44.0f)) {
      float mnew = fmaxf(m_run, vmax);
      float alpha = exp2f((m_run - mnew) * CEXP);
      l_run *= alpha;
#pragma unroll
      for (int c2 = 0; c2 < 4; ++c2)
#pragma unroll
        for (int j = 0; j < 4; ++j) oacc[c2][j] *= alpha;
      m_run = mnew;
    }

    // exp + row sum (scale folded into CEXP)
    float rs = 0.0f;
#pragma unroll
    for (int c = 0; c < 4; ++c)
#pragma unroll
      for (int j = 0; j < 4; ++j) {
        float p = exp2f((sc[c][j] - m_run) * CEXP);
        sc[c][j] = p;
        rs += p;
      }
    rs += __shfl_xor(rs, 16);
    rs += __shfl_xor(rs, 32);
    l_run += rs;

    // pack P in-register -> PV B-fragments (kv = 32h + 8g + m; m = 4(c&1)+j)
    union { short8 s8; uint32_t w[4]; } pa[2];
#pragma unroll
    for (int h = 0; h < 2; ++h)
#pragma unroll
      for (int i = 0; i < 4; ++i) {
        float lo = sc[2 * h + (i >> 1)][(i & 1) * 2];
        float hi = sc[2 * h + (i >> 1)][(i & 1) * 2 + 1];
        asm("v_cvt_pk_bf16_f32 %0, %1, %2" : "=v"(pa[h].w[i]) : "v"(lo), "v"(hi));
      }

    // PV: O^T[d][q] += V^T-frag (A, rows=d) x P-frag (B, rows=q)
#pragma unroll
    for (int c2 = 0; c2 < 4; ++c2) {
#pragma unroll
      for (int h = 0; h < 2; ++h) {
        short8 av = *(const short8*)&Vt[c2 * 16 + l15][h * 32 + 8 * g];
        oacc[c2] = __builtin_amdgcn_mfma_f32_16x16x32_bf16(av, pa[h].s8,
                                                           oacc[c2], 0, 0, 0);
      }
    }
  }

  // epilogue: normalize, transpose through LDS (per-wave region), coalesced store
  float inv = 1.0f / l_run;
  __syncthreads();  // all waves done with Vt
  u16* ow = &Vt[0][0] + wid * 16 * 72;          // 16 rows x 72 per wave
#pragma unroll
  for (int c2 = 0; c2 < 4; ++c2)
#pragma unroll
    for (int jp = 0; jp < 2; ++jp) {
      float lo = oacc[c2][2 * jp] * inv, hi = oacc[c2][2 * jp + 1] * inv;
      uint32_t w;
      asm("v_cvt_pk_bf16_f32 %0, %1, %2" : "=v"(w) : "v"(lo), "v"(hi));
      *(uint32_t*)&ow[l15 * 72 + c2 * 16 + 4 * g + 2 * jp] = w;
    }
  __syncthreads();
  int r = lane >> 2, dc = (lane & 3) * 16;
  short8 o0 = *(const short8*)&ow[r * 72 + dc];
  short8 o1 = *(const short8*)&ow[r * 72 + dc + 8];
  int b = bh >> 4, hh = bh & 15;
  size_t xo = ((size_t)b * SEQ + qw + r) * EMB + hh * 64 + dc;
  *(short8*)&X[xo] = o0;
  *(short8*)&X[xo + 8] = o1;
}

// ---------------- host ----------------
extern "C" void kernel_launch(void* const* d_in, const int* in_sizes, int n_in,
                              void* d_out, int out_size, void* d_ws, size_t ws_size,
                              hipStream_t stream) {
  const float* q  = (const float*)d_in[0];
  const float* k  = (const float*)d_in[1];
  const float* v  = (const float*)d_in[2];
  const float* wq = (const float*)d_in[4];
  const float* bq = (const float*)d_in[5];
  const float* wk = (const float*)d_in[6];
  const float* bk = (const float*)d_in[7];
  const float* wv = (const float*)d_in[8];
  const float* bv = (const float*)d_in[9];
  const float* wo = (const float*)d_in[10];
  const float* bo = (const float*)d_in[11];

  u16* Aall = (u16*)d_ws;                                 // 3 x [4096,1024] bf16
  u16* Wall = Aall + (size_t)3 * MTOT * EMB;              // 4 x [1024,1024] bf16
  u16* QKVh = Wall + (size_t)4 * EMB * EMB;               // 3 x [B,H,S,64] bf16
  u16* Xb   = QKVh + (size_t)3 * MTOT * EMB;              // [4096,1024] bf16

  cvt3<<<dim3(MTOT * EMB / 4 / 256, 3), 256, 0, stream>>>(q, k, v, Aall);
  cvt4<<<dim3(EMB * EMB / 4 / 256, 4), 256, 0, stream>>>(wq, wk, wv, wo, Wall);

  // QKV projections -> head layout
  dim3 gq(EMB / 128, MTOT / 128, 3);
  gemm_qkv<<<gq, 256, 0, stream>>>(Aall, Wall, bq, bk, bv, QKVh);

  // flash attention -> Xb [4096,1024] bf16
  const u16* Qh = QKVh;
  const u16* Kh = QKVh + (size_t)MTOT * EMB;
  const u16* Vh = QKVh + (size_t)2 * MTOT * EMB;
  flash_attn<<<1024, 256, 0, stream>>>(Qh, Kh, Vh, Xb);

  // output projection -> fp32 d_out
  dim3 go(EMB / 128, MTOT / 128);
  gemm_out<<<go, 256, 0, stream>>>(Xb, Wall + (size_t)3 * EMB * EMB, bo, (float*)d_out);
}

// Round 4
// 165.844 us; speedup vs baseline: 1.3589x; 1.3589x over previous
//
#include <hip/hip_runtime.h>
#include <stdint.h>

// ---- types ----
typedef __attribute__((ext_vector_type(8))) short short8;   // 8 bf16 (4 VGPRs)
typedef __attribute__((ext_vector_type(4))) float f32x4;    // MFMA acc
typedef unsigned short u16;

// B=2, S=2048, E=1024, H=16, DK=64
#define SEQ 2048
#define EMB 1024
#define NH 16
#define DK 64
#define MTOT 4096   // B*S
#define CEXP 0.18033688011112042f   // 0.125 * log2(e): fold qk-scale into exp2

__device__ __forceinline__ u16 f2bf(float f) {
  union { float f; unsigned int u; } x; x.f = f;
  unsigned int r = x.u + 0x7fffu + ((x.u >> 16) & 1u);  // RNE
  return (u16)(r >> 16);
}

// async global->LDS, 16B per lane. LDS dest = wave-uniform base + lane*16.
__device__ __forceinline__ void gload_lds16(const void* g, void* l) {
  __builtin_amdgcn_global_load_lds(
      (const __attribute__((address_space(1))) unsigned int*)g,
      (__attribute__((address_space(3))) unsigned int*)l,
      16, 0, 0);
}

// ---------------- fp32 -> bf16 converts (fused launches) ----------------
__global__ __launch_bounds__(256) void cvt3(const float* __restrict__ a,
                                            const float* __restrict__ b,
                                            const float* __restrict__ c,
                                            u16* __restrict__ d) {
  const float* s = (blockIdx.y == 0) ? a : ((blockIdx.y == 1) ? b : c);
  size_t base = (size_t)blockIdx.y * (MTOT * (size_t)EMB / 4);
  int i = blockIdx.x * 256 + threadIdx.x;
  float4 v = ((const float4*)s)[i];
  ushort4 o;
  o.x = f2bf(v.x); o.y = f2bf(v.y); o.z = f2bf(v.z); o.w = f2bf(v.w);
  ((ushort4*)d)[base + i] = o;
}

__global__ __launch_bounds__(256) void cvt4(const float* __restrict__ a,
                                            const float* __restrict__ b,
                                            const float* __restrict__ c,
                                            const float* __restrict__ e,
                                            u16* __restrict__ d) {
  const float* s = (blockIdx.y == 0) ? a
                 : ((blockIdx.y == 1) ? b : ((blockIdx.y == 2) ? c : e));
  size_t base = (size_t)blockIdx.y * ((size_t)EMB * EMB / 4);
  int i = blockIdx.x * 256 + threadIdx.x;
  float4 v = ((const float4*)s)[i];
  ushort4 o;
  o.x = f2bf(v.x); o.y = f2bf(v.y); o.z = f2bf(v.z); o.w = f2bf(v.w);
  ((ushort4*)d)[base + i] = o;
}

// ---------------- GEMM core: C[M,N] = A[M,K] @ W[N,K]^T + bias ----------------
// BM=BN=128, BK=64, 256 threads = 4 waves (2x2), each wave 64x64 (4x4 frags).
// MODE 0: store bf16 into [B,H,S,DK] head layout. MODE 1: store fp32 flat [M,N].
template <int MODE>
__device__ __forceinline__ void gemm_core(const u16* __restrict__ A,
                                          const u16* __restrict__ W,
                                          const float* __restrict__ bias,
                                          void* __restrict__ dst,
                                          int m0, int n0,
                                          u16* As, u16* Bs) {
  const int K = EMB;
  int tid = threadIdx.x, lane = tid & 63, wid = tid >> 6;
  int g = lane >> 4, l15 = lane & 15;
  int wr = wid >> 1, wc = wid & 1;

  f32x4 acc[4][4];
#pragma unroll
  for (int mi = 0; mi < 4; ++mi)
#pragma unroll
    for (int ni = 0; ni < 4; ++ni) acc[mi][ni] = (f32x4)(0.0f);

  for (int kt = 0; kt < K / 64; ++kt) {
    int k0 = kt * 64;
#pragma unroll
    for (int i = 0; i < 4; ++i) {
      int off = (wid * 4 + i) * 1024;          // byte offset into tile
      int elem = (off >> 1) + lane * 8;        // bf16 element index
      int row = elem >> 6, col = elem & 63;
      gload_lds16(A + (size_t)(m0 + row) * K + k0 + col, (char*)As + off);
      gload_lds16(W + (size_t)(n0 + row) * K + k0 + col, (char*)Bs + off);
    }
    __syncthreads();  // drains vmcnt
#pragma unroll
    for (int kk = 0; kk < 2; ++kk) {
      short8 af[4], bf[4];
#pragma unroll
      for (int mi = 0; mi < 4; ++mi)
        af[mi] = *(const short8*)&As[(wr * 64 + mi * 16 + l15) * 64 + kk * 32 + 8 * g];
#pragma unroll
      for (int ni = 0; ni < 4; ++ni)
        bf[ni] = *(const short8*)&Bs[(wc * 64 + ni * 16 + l15) * 64 + kk * 32 + 8 * g];
#pragma unroll
      for (int mi = 0; mi < 4; ++mi)
#pragma unroll
        for (int ni = 0; ni < 4; ++ni)
          acc[mi][ni] = __builtin_amdgcn_mfma_f32_16x16x32_bf16(af[mi], bf[ni],
                                                                acc[mi][ni], 0, 0, 0);
    }
    __syncthreads();
  }

  // epilogue: D layout col=lane&15, row=(lane>>4)*4+j  [m89-verified]
#pragma unroll
  for (int ni = 0; ni < 4; ++ni) {
    int n_g = n0 + wc * 64 + ni * 16 + l15;
    float bv = bias[n_g];
#pragma unroll
    for (int mi = 0; mi < 4; ++mi) {
#pragma unroll
      for (int j = 0; j < 4; ++j) {
        int m_g = m0 + wr * 64 + mi * 16 + 4 * g + j;
        float v = acc[mi][ni][j] + bv;
        if (MODE == 0) {
          int b = m_g >> 11, s = m_g & (SEQ - 1);
          int h = n_g >> 6, d = n_g & 63;
          ((u16*)dst)[((((size_t)b * NH + h) * SEQ + s) << 6) + d] = f2bf(v);
        } else {
          ((float*)dst)[(size_t)m_g * EMB + n_g] = v;
        }
      }
    }
  }
}

__global__ __launch_bounds__(256, 2) void gemm_qkv(const u16* __restrict__ Aall,
                                                   const u16* __restrict__ Wall,
                                                   const float* __restrict__ bq,
                                                   const float* __restrict__ bk,
                                                   const float* __restrict__ bv,
                                                   u16* __restrict__ QKVh) {
  __shared__ __align__(16) u16 As[128 * 64];
  __shared__ __align__(16) u16 Bs[128 * 64];
  int z = blockIdx.z;
  const u16* A = Aall + (size_t)z * MTOT * EMB;
  const u16* W = Wall + (size_t)z * EMB * EMB;
  const float* bias = (z == 0) ? bq : ((z == 1) ? bk : bv);
  u16* dst = QKVh + (size_t)z * MTOT * EMB;
  gemm_core<0>(A, W, bias, dst, blockIdx.y * 128, blockIdx.x * 128, As, Bs);
}

__global__ __launch_bounds__(256, 2) void gemm_out(const u16* __restrict__ X,
                                                   const u16* __restrict__ Wo,
                                                   const float* __restrict__ bo,
                                                   float* __restrict__ out) {
  __shared__ __align__(16) u16 As[128 * 64];
  __shared__ __align__(16) u16 Bs[128 * 64];
  gemm_core<1>(X, Wo, bo, out, blockIdx.y * 128, blockIdx.x * 128, As, Bs);
}

// ---------------- flash attention (causal), v3 ----------------
// 1024 blocks. Decode: xcd = bl&7, idx = bl>>3, c = idx&31 (CU slot), r = idx>>5
// (fill round). bh = xcd*4 + r keeps 4 bh per XCD (K/V/Q L2-resident, ~3MB).
// qt(c,r) = {c, 31-c, (c+16)&31, 31-((c+16)&31)} -> each (bh,qt) covered once AND
// each CU slot's 4 rounds sum to exactly 66 tiles (balanced, heavy+light mixed).
//
// Pipeline per kv-tile (ONE barrier per tile):
//   issue V(t+1) global loads (T14 async-stage)    } hidden under
//   QK^T (K direct from L2) + softmax + PV(buf[t&1]) } compute
//   ds_write V(t+1) -> buf[(t+1)&1]; __syncthreads()
//
// QK^T swapped: sc = mfma(K_perm, Q) -> lane owns q = qw+(lane&15), kv in regs
// matching the PV B-fragment layout exactly (see sigma comment in round 2).
__global__ __launch_bounds__(256, 4) void flash_attn(const u16* __restrict__ Qh,
                                                     const u16* __restrict__ Kh,
                                                     const u16* __restrict__ Vh,
                                                     u16* __restrict__ X) {
  __shared__ __align__(16) u16 Vt[2][64][72];   // double-buffered [d][kv], pad 144B

  int tid = threadIdx.x, lane = tid & 63, wid = tid >> 6;
  int g = lane >> 4, l15 = lane & 15;

  int bl = blockIdx.x;
  int xcd = bl & 7, idx = bl >> 3;
  int c = idx & 31, r = idx >> 5;
  int bh = xcd * 4 + r;
  int cc = (r >= 2) ? ((c + 16) & 31) : c;
  int qt = (r & 1) ? (31 - cc) : cc;            // balanced qt per CU slot

  int q0 = qt * 64, qw = q0 + wid * 16;
  int qrow = qw + l15;                          // this lane's q row

  // Q fragment (B-operand): rows q = qw+l15, k = 8g+j (halves at +0 / +32)
  const short8* qp = (const short8*)(Qh + ((size_t)bh * SEQ + qrow) * DK + 8 * g);
  short8 fq0 = qp[0], fq1 = qp[4];

  int kvbase = 8 * (l15 >> 2) + (l15 & 3);      // sigma row base for this lane
  const u16* Kb = Kh + (size_t)bh * SEQ * DK;
  const u16* Vb = Vh + (size_t)bh * SEQ * DK;

  f32x4 sc[4], oacc[4];
#pragma unroll
  for (int i = 0; i < 4; ++i) oacc[i] = (f32x4)(0.0f);
  float m_run = -1e30f, l_run = 0.0f;

  // prologue: stage V(0) into buf 0
  {
#pragma unroll
    for (int it = 0; it < 2; ++it) {
      int kvb = wid * 8 + it * 32;
      short8 tmp;
#pragma unroll
      for (int i = 0; i < 8; ++i)
        tmp[i] = (short)Vb[(size_t)(kvb + i) * DK + lane];
      *(short8*)&Vt[0][lane][kvb] = tmp;
    }
  }
  __syncthreads();

  for (int t = 0; t <= qt; ++t) {
    int kv0 = t * 64;
    int cur = t & 1;

    // T14: issue next-tile V loads FIRST (latency hides under this tile's compute)
    u16 vtmp[16];
    if (t < qt) {
      int kvn = kv0 + 64;
#pragma unroll
      for (int it = 0; it < 2; ++it)
#pragma unroll
        for (int i = 0; i < 8; ++i)
          vtmp[it * 8 + i] = Vb[(size_t)(kvn + wid * 8 + it * 32 + i) * DK + lane];
    }

    // QK^T swapped, K rows permuted by sigma (direct from global/L2)
    const u16* krow = Kb + (size_t)(kv0 + kvbase) * DK + 8 * g;
#pragma unroll
    for (int cq = 0; cq < 4; ++cq) {
      const u16* kc = krow + (size_t)(4 * (cq & 1) + 32 * (cq >> 1)) * DK;
      short8 k0 = *(const short8*)kc;
      short8 k1 = *(const short8*)(kc + 32);
      f32x4 z = (f32x4)(0.0f);
      z = __builtin_amdgcn_mfma_f32_16x16x32_bf16(k0, fq0, z, 0, 0, 0);
      z = __builtin_amdgcn_mfma_f32_16x16x32_bf16(k1, fq1, z, 0, 0, 0);
      sc[cq] = z;
    }

    // causal mask (diag tile only); lane's sc[cq][j] is kv = kv0+8g+4(cq&1)+32(cq>>1)+j
    if (t == qt) {
#pragma unroll
      for (int cq = 0; cq < 4; ++cq) {
        int kvc = kv0 + 8 * g + 4 * (cq & 1) + 32 * (cq >> 1);
#pragma unroll
        for (int j = 0; j < 4; ++j)
          if (kvc + j > qrow) sc[cq][j] = -1e30f;
      }
    }

    // row max: 15 in-register + 2 shfl (lanes l15, +16, +32, +48 share q)
    float vmax = sc[0][0];
#pragma unroll
    for (int cq = 0; cq < 4; ++cq)
#pragma unroll
      for (int j = 0; j < 4; ++j) vmax = fmaxf(vmax, sc[cq][j]);
    vmax = fmaxf(vmax, __shfl_xor(vmax, 16));
    vmax = fmaxf(vmax, __shfl_xor(vmax, 32));

    // defer-max (T13): raw-score threshold 44 -> p bounded by ~2^8
    if (!__all(vmax - m_run <= 44.0f)) {
      float mnew = fmaxf(m_run, vmax);
      float alpha = exp2f((m_run - mnew) * CEXP);
      l_run *= alpha;
#pragma unroll
      for (int c2 = 0; c2 < 4; ++c2)
#pragma unroll
        for (int j = 0; j < 4; ++j) oacc[c2][j] *= alpha;
      m_run = mnew;
    }

    // exp + row sum (scale folded into CEXP)
    float rs = 0.0f;
#pragma unroll
    for (int cq = 0; cq < 4; ++cq)
#pragma unroll
      for (int j = 0; j < 4; ++j) {
        float p = exp2f((sc[cq][j] - m_run) * CEXP);
        sc[cq][j] = p;
        rs += p;
      }
    rs += __shfl_xor(rs, 16);
    rs += __shfl_xor(rs, 32);
    l_run += rs;

    // pack P in-register -> PV B-fragments (kv = 32h + 8g + m; m = 4(cq&1)+j)
    union { short8 s8; uint32_t w[4]; } pa[2];
#pragma unroll
    for (int h = 0; h < 2; ++h)
#pragma unroll
      for (int i = 0; i < 4; ++i) {
        float lo = sc[2 * h + (i >> 1)][(i & 1) * 2];
        float hi = sc[2 * h + (i >> 1)][(i & 1) * 2 + 1];
        asm("v_cvt_pk_bf16_f32 %0, %1, %2" : "=v"(pa[h].w[i]) : "v"(lo), "v"(hi));
      }

    // PV: O^T[d][q] += V^T-frag (A, rows=d) x P-frag (B, rows=q), from buf[cur]
#pragma unroll
    for (int c2 = 0; c2 < 4; ++c2) {
#pragma unroll
      for (int h = 0; h < 2; ++h) {
        short8 av = *(const short8*)&Vt[cur][c2 * 16 + l15][h * 32 + 8 * g];
        oacc[c2] = __builtin_amdgcn_mfma_f32_16x16x32_bf16(av, pa[h].s8,
                                                           oacc[c2], 0, 0, 0);
      }
    }

    // write staged V(t+1) into the other buffer, then the single barrier
    if (t < qt) {
#pragma unroll
      for (int it = 0; it < 2; ++it) {
        short8 w;
#pragma unroll
        for (int i = 0; i < 8; ++i) w[i] = (short)vtmp[it * 8 + i];
        *(short8*)&Vt[cur ^ 1][lane][wid * 8 + it * 32] = w;
      }
    }
    __syncthreads();
  }

  // epilogue: normalize, transpose through LDS (per-wave region), coalesced store
  float inv = 1.0f / l_run;
  u16* ow = &Vt[0][0][0] + wid * 16 * 72;       // 16 rows x 72 per wave (buf 0)
#pragma unroll
  for (int c2 = 0; c2 < 4; ++c2)
#pragma unroll
    for (int jp = 0; jp < 2; ++jp) {
      float lo = oacc[c2][2 * jp] * inv, hi = oacc[c2][2 * jp + 1] * inv;
      uint32_t w;
      asm("v_cvt_pk_bf16_f32 %0, %1, %2" : "=v"(w) : "v"(lo), "v"(hi));
      *(uint32_t*)&ow[l15 * 72 + c2 * 16 + 4 * g + 2 * jp] = w;
    }
  __syncthreads();
  int rr = lane >> 2, dc = (lane & 3) * 16;
  short8 o0 = *(const short8*)&ow[rr * 72 + dc];
  short8 o1 = *(const short8*)&ow[rr * 72 + dc + 8];
  int b = bh >> 4, hh = bh & 15;
  size_t xo = ((size_t)b * SEQ + qw + rr) * EMB + hh * 64 + dc;
  *(short8*)&X[xo] = o0;
  *(short8*)&X[xo + 8] = o1;
}

// ---------------- host ----------------
extern "C" void kernel_launch(void* const* d_in, const int* in_sizes, int n_in,
                              void* d_out, int out_size, void* d_ws, size_t ws_size,
                              hipStream_t stream) {
  const float* q  = (const float*)d_in[0];
  const float* k  = (const float*)d_in[1];
  const float* v  = (const float*)d_in[2];
  const float* wq = (const float*)d_in[4];
  const float* bq = (const float*)d_in[5];
  const float* wk = (const float*)d_in[6];
  const float* bk = (const float*)d_in[7];
  const float* wv = (const float*)d_in[8];
  const float* bv = (const float*)d_in[9];
  const float* wo = (const float*)d_in[10];
  const float* bo = (const float*)d_in[11];

  u16* Aall = (u16*)d_ws;                                 // 3 x [4096,1024] bf16
  u16* Wall = Aall + (size_t)3 * MTOT * EMB;              // 4 x [1024,1024] bf16
  u16* QKVh = Wall + (size_t)4 * EMB * EMB;               // 3 x [B,H,S,64] bf16
  u16* Xb   = QKVh + (size_t)3 * MTOT * EMB;              // [4096,1024] bf16

  cvt3<<<dim3(MTOT * EMB / 4 / 256, 3), 256, 0, stream>>>(q, k, v, Aall);
  cvt4<<<dim3(EMB * EMB / 4 / 256, 4), 256, 0, stream>>>(wq, wk, wv, wo, Wall);

  // QKV projections -> head layout
  dim3 gq(EMB / 128, MTOT / 128, 3);
  gemm_qkv<<<gq, 256, 0, stream>>>(Aall, Wall, bq, bk, bv, QKVh);

  // flash attention -> Xb [4096,1024] bf16
  const u16* Qh = QKVh;
  const u16* Kh = QKVh + (size_t)MTOT * EMB;
  const u16* Vh = QKVh + (size_t)2 * MTOT * EMB;
  flash_attn<<<1024, 256, 0, stream>>>(Qh, Kh, Vh, Xb);

  // output projection -> fp32 d_out
  dim3 go(EMB / 128, MTOT / 128);
  gemm_out<<<go, 256, 0, stream>>>(Xb, Wall + (size_t)3 * EMB * EMB, bo, (float*)d_out);
}